// Round 1
// baseline (42066.013 us; speedup 1.0000x reference)
//
#include <hip/hip_runtime.h>
#include <math.h>

#define NN 4096
#define TT 365
#define FF 16
#define HH 32
#define RPB 16      // rows per block
#define KC 128      // k-chunk staged in LDS
#define NCHUNK (NN / KC)

__device__ __forceinline__ float sigf(float x) {
    return 1.0f / (1.0f + __expf(-x));
}
__device__ __forceinline__ float thf(float x) {
    x = fminf(fmaxf(x, -15.0f), 15.0f);
    float e = __expf(2.0f * x);
    return (e - 1.0f) / (e + 1.0f);
}

__global__ __launch_bounds__(256)
void init_kernel(float* __restrict__ G0, float* __restrict__ hs, float* __restrict__ cs,
                 const float* __restrict__ bgh, const float* __restrict__ bgc) {
    int i = blockIdx.x * 256 + threadIdx.x;
    if (i < NN * 64) {
        int c = i & 63;
        G0[i] = (c < HH) ? bgh[c] : bgc[c - HH];
    }
    if (i < NN * HH) { hs[i] = 0.0f; cs[i] = 0.0f; }
}

// One time step. Block owns RPB=16 rows.
// Phase 1: HG|CG = tanh(A[rows,:] @ G[:,0:64])   (G cols 0-31 = G_h, 32-63 = G_c)
// Phase 2: row-local LSTM cell + fusion + write G(t+1), h/c state, fused output head.
__global__ __launch_bounds__(256)
void step_kernel(const float* __restrict__ A, const float* __restrict__ x,
                 const float* __restrict__ W_out, const float* __restrict__ b_out,
                 const float* __restrict__ Wgh, const float* __restrict__ bgh,
                 const float* __restrict__ Wgc, const float* __restrict__ bgc,
                 const float* __restrict__ Whc, const float* __restrict__ Whp,
                 const float* __restrict__ bh,
                 const float* __restrict__ Wcc, const float* __restrict__ Wcp,
                 const float* __restrict__ bc,
                 const float* __restrict__ K, const float* __restrict__ R,
                 const float* __restrict__ bias,
                 const float* __restrict__ Gin, float* __restrict__ Gout,
                 float* __restrict__ h_state, float* __restrict__ c_state,
                 float* __restrict__ out, int t)
{
    // LDS layout (floats): [0,8192) ldsG (phase1) / gts[16][129] (phase2 alias)
    // [8192,10240) ldsA ; [10240,11280) hgcg[16][65] ; rest: small padded arrays
    __shared__ float smem[14704];
    float* ldsG  = smem;
    float* gts   = smem;                    // phase-2 alias of ldsG region
    float* ldsA  = smem + 8192;
    float* hgcg  = smem + 10240;            // [16][65]
    float* sarr  = smem + 11280;
    float* hprev = sarr;                    // [16][33]
    float* cprev = sarr + 528;
    float* hcur  = sarr + 1056;
    float* ccur  = sarr + 1584;
    float* hupd  = sarr + 2112;
    float* cupd  = sarr + 2640;
    float* xs    = sarr + 3168;             // [16][16]

    const int tid  = threadIdx.x;
    const int base = blockIdx.x * RPB;

    // ---------------- phase 1: big matmul ----------------
    const int w4   = (tid >> 6) << 2;   // wave id * 4 rows
    const int lane = tid & 63;          // output column 0..63
    float acc0 = 0.f, acc1 = 0.f, acc2 = 0.f, acc3 = 0.f;

    for (int ch = 0; ch < NCHUNK; ++ch) {
        const int k0 = ch * KC;
        // stage G chunk [KC][64] (linear float4, coalesced, conflict-free)
        const float4* gsrc = (const float4*)(Gin + (size_t)k0 * 64);
        float4* gdst = (float4*)ldsG;
        #pragma unroll
        for (int i = 0; i < (KC * 64 / 4) / 256; ++i)     // 8 iters
            gdst[tid + i * 256] = gsrc[tid + i * 256];
        // stage A chunk [16][KC]
        #pragma unroll
        for (int i = 0; i < (RPB * KC / 4) / 256; ++i) {  // 2 iters
            int idx = tid + i * 256;
            int r   = idx >> 5;         // KC/4 = 32 float4 per row
            int kk4 = idx & 31;
            ((float4*)ldsA)[idx] =
                *(const float4*)(A + (size_t)(base + r) * NN + k0 + kk4 * 4);
        }
        __syncthreads();
        #pragma unroll 4
        for (int kk = 0; kk < KC; kk += 4) {
            float4 a0 = *(const float4*)(ldsA + (w4 + 0) * KC + kk);
            float4 a1 = *(const float4*)(ldsA + (w4 + 1) * KC + kk);
            float4 a2 = *(const float4*)(ldsA + (w4 + 2) * KC + kk);
            float4 a3 = *(const float4*)(ldsA + (w4 + 3) * KC + kk);
            float g0 = ldsG[(kk + 0) * 64 + lane];
            float g1 = ldsG[(kk + 1) * 64 + lane];
            float g2 = ldsG[(kk + 2) * 64 + lane];
            float g3 = ldsG[(kk + 3) * 64 + lane];
            acc0 = fmaf(a0.w, g3, fmaf(a0.z, g2, fmaf(a0.y, g1, fmaf(a0.x, g0, acc0))));
            acc1 = fmaf(a1.w, g3, fmaf(a1.z, g2, fmaf(a1.y, g1, fmaf(a1.x, g0, acc1))));
            acc2 = fmaf(a2.w, g3, fmaf(a2.z, g2, fmaf(a2.y, g1, fmaf(a2.x, g0, acc2))));
            acc3 = fmaf(a3.w, g3, fmaf(a3.z, g2, fmaf(a3.y, g1, fmaf(a3.x, g0, acc3))));
        }
        __syncthreads();
    }
    hgcg[(w4 + 0) * 65 + lane] = thf(acc0);
    hgcg[(w4 + 1) * 65 + lane] = thf(acc1);
    hgcg[(w4 + 2) * 65 + lane] = thf(acc2);
    hgcg[(w4 + 3) * 65 + lane] = thf(acc3);

    // ---------------- phase 2: row-local ----------------
    const int r2 = tid >> 4;        // local row 0..15
    const int j  = tid & 15;
    const int d0 = 2 * j, d1 = 2 * j + 1;   // this thread's two h-dims
    const int row = base + r2;

    {
        float2 hp = *(const float2*)(h_state + (size_t)row * HH + d0);
        float2 cp = *(const float2*)(c_state + (size_t)row * HH + d0);
        hprev[r2 * 33 + d0] = hp.x; hprev[r2 * 33 + d1] = hp.y;
        cprev[r2 * 33 + d0] = cp.x; cprev[r2 * 33 + d1] = cp.y;
        xs[r2 * 16 + j] = x[((size_t)row * TT + t) * FF + j];
    }
    __syncthreads();   // also separates phase-1 hgcg writes / ldsG last reads

    // gates for contiguous dims [j*8, j*8+8)
    float g8[8];
    #pragma unroll
    for (int q = 0; q < 8; ++q) g8[q] = bias[j * 8 + q];
    #pragma unroll
    for (int f = 0; f < FF; ++f) {
        float xv = xs[r2 * 16 + f];
        const float4* k4 = (const float4*)(K + f * 128 + j * 8);
        float4 ka = k4[0], kb = k4[1];
        g8[0] += xv * ka.x; g8[1] += xv * ka.y; g8[2] += xv * ka.z; g8[3] += xv * ka.w;
        g8[4] += xv * kb.x; g8[5] += xv * kb.y; g8[6] += xv * kb.z; g8[7] += xv * kb.w;
    }
    #pragma unroll
    for (int i = 0; i < HH; ++i) {
        float hv = hprev[r2 * 33 + i];
        const float4* r4 = (const float4*)(R + i * 128 + j * 8);
        float4 ra = r4[0], rb = r4[1];
        g8[0] += hv * ra.x; g8[1] += hv * ra.y; g8[2] += hv * ra.z; g8[3] += hv * ra.w;
        g8[4] += hv * rb.x; g8[5] += hv * rb.y; g8[6] += hv * rb.z; g8[7] += hv * rb.w;
    }
    #pragma unroll
    for (int q = 0; q < 8; ++q) gts[r2 * 129 + j * 8 + q] = g8[q];
    __syncthreads();

    // LSTM cell for dims d0, d1  (gate order i,f,g,o)
    float gi0 = gts[r2 * 129 + d0],      gi1 = gts[r2 * 129 + d1];
    float gf0 = gts[r2 * 129 + 32 + d0], gf1 = gts[r2 * 129 + 32 + d1];
    float gg0 = gts[r2 * 129 + 64 + d0], gg1 = gts[r2 * 129 + 64 + d1];
    float go0 = gts[r2 * 129 + 96 + d0], go1 = gts[r2 * 129 + 96 + d1];
    float cc0 = sigf(gf0) * cprev[r2 * 33 + d0] + sigf(gi0) * thf(gg0);
    float cc1 = sigf(gf1) * cprev[r2 * 33 + d1] + sigf(gi1) * thf(gg1);
    float hc0 = sigf(go0) * thf(cc0);
    float hc1 = sigf(go1) * thf(cc1);
    hcur[r2 * 33 + d0] = hc0; hcur[r2 * 33 + d1] = hc1;
    ccur[r2 * 33 + d0] = cc0; ccur[r2 * 33 + d1] = cc1;
    __syncthreads();

    // fusion updates
    float s0 = bh[d0], s1 = bh[d1], u0 = bc[d0], u1 = bc[d1];
    #pragma unroll
    for (int i = 0; i < HH; ++i) {
        float hcv = hcur[r2 * 33 + i], hgv = hgcg[r2 * 65 + i];
        float ccv = ccur[r2 * 33 + i], cgv = hgcg[r2 * 65 + 32 + i];
        float2 whc = *(const float2*)(Whc + i * 32 + d0);
        float2 whp = *(const float2*)(Whp + i * 32 + d0);
        float2 wcc = *(const float2*)(Wcc + i * 32 + d0);
        float2 wcp = *(const float2*)(Wcp + i * 32 + d0);
        s0 += hcv * whc.x + hgv * whp.x;  s1 += hcv * whc.y + hgv * whp.y;
        u0 += ccv * wcc.x + cgv * wcp.x;  u1 += ccv * wcc.y + cgv * wcp.y;
    }
    float hu0 = sigf(s0), hu1 = sigf(s1), cu0 = sigf(u0), cu1 = sigf(u1);
    hupd[r2 * 33 + d0] = hu0; hupd[r2 * 33 + d1] = hu1;
    cupd[r2 * 33 + d0] = cu0; cupd[r2 * 33 + d1] = cu1;
    *(float2*)(h_state + (size_t)row * HH + d0) = make_float2(hu0, hu1);
    *(float2*)(c_state + (size_t)row * HH + d0) = make_float2(cu0, cu1);
    __syncthreads();

    // G(t+1) for this row (cols d0,d1 of G_h and G_c)
    float gh0 = bgh[d0], gh1 = bgh[d1], gc0 = bgc[d0], gc1 = bgc[d1];
    #pragma unroll
    for (int i = 0; i < HH; ++i) {
        float hv = hupd[r2 * 33 + i], cv = cupd[r2 * 33 + i];
        float2 wgh = *(const float2*)(Wgh + i * 32 + d0);
        float2 wgc = *(const float2*)(Wgc + i * 32 + d0);
        gh0 += hv * wgh.x; gh1 += hv * wgh.y;
        gc0 += cv * wgc.x; gc1 += cv * wgc.y;
    }
    *(float2*)(Gout + (size_t)row * 64 + d0)      = make_float2(gh0, gh1);
    *(float2*)(Gout + (size_t)row * 64 + 32 + d0) = make_float2(gc0, gc1);

    // fused output head: out[t*N + row] = h_upd . W_out + b_out
    float p = hu0 * W_out[d0] + hu1 * W_out[d1];
    #pragma unroll
    for (int off = 8; off; off >>= 1) p += __shfl_down(p, off, 16);
    if (j == 0) out[(size_t)t * NN + row] = p + b_out[0];
}

extern "C" void kernel_launch(void* const* d_in, const int* in_sizes, int n_in,
                              void* d_out, int out_size, void* d_ws, size_t ws_size,
                              hipStream_t stream)
{
    const float* x     = (const float*)d_in[0];
    const float* A     = (const float*)d_in[1];
    const float* W_out = (const float*)d_in[2];
    const float* b_out = (const float*)d_in[3];
    const float* Wgh   = (const float*)d_in[4];
    const float* bgh   = (const float*)d_in[5];
    const float* Wgc   = (const float*)d_in[6];
    const float* bgc   = (const float*)d_in[7];
    const float* Whc   = (const float*)d_in[8];
    const float* Whp   = (const float*)d_in[9];
    const float* bh    = (const float*)d_in[10];
    const float* Wcc   = (const float*)d_in[11];
    const float* Wcp   = (const float*)d_in[12];
    const float* bc    = (const float*)d_in[13];
    const float* K     = (const float*)d_in[14];
    const float* R     = (const float*)d_in[15];
    const float* bias  = (const float*)d_in[16];
    float* out = (float*)d_out;

    // workspace: G double-buffer + h/c state (3 MB)
    float* G0 = (float*)d_ws;
    float* G1 = G0 + NN * 64;
    float* hs = G1 + NN * 64;
    float* cs = hs + NN * HH;

    init_kernel<<<dim3(NN * 64 / 256), dim3(256), 0, stream>>>(G0, hs, cs, bgh, bgc);
    for (int t = 0; t < TT; ++t) {
        const float* Gin = (t & 1) ? G1 : G0;
        float*       Gout = (t & 1) ? G0 : G1;
        step_kernel<<<dim3(NN / RPB), dim3(256), 0, stream>>>(
            A, x, W_out, b_out, Wgh, bgh, Wgc, bgc, Whc, Whp, bh,
            Wcc, Wcp, bc, K, R, bias, Gin, Gout, hs, cs, out, t);
    }
}

// Round 2
// 11364.821 us; speedup vs baseline: 3.7014x; 3.7014x over previous
//
#include <hip/hip_runtime.h>
#include <math.h>

#define NN 4096
#define TT 365
#define FF 16
#define HH 32

typedef unsigned short u16;
typedef __attribute__((ext_vector_type(8))) short bf16x8;
typedef __attribute__((ext_vector_type(4))) float f32x4;

__device__ __forceinline__ float sigf(float x){ return 1.0f/(1.0f+__expf(-x)); }
__device__ __forceinline__ float thf(float x){
    x = fminf(fmaxf(x,-15.0f),15.0f);
    float e = __expf(2.0f*x);
    return (e-1.0f)/(e+1.0f);
}
__device__ __forceinline__ u16 f2bf(float f){
    unsigned u = __float_as_uint(f);
    u += 0x7FFF + ((u>>16)&1);
    return (u16)(u>>16);
}
__device__ __forceinline__ float bf2f(u16 h){
    return __uint_as_float(((unsigned)h)<<16);
}

// Pre-pack A (fp32 [4096][4096]) into MFMA A-fragment order, split bf16 hi/lo.
// Fragment addr (bf16x8 units): (rb*128 + kt)*64 + lane
//   lane&15 = local row m, lane>>4 = k-subgroup (8 consecutive k each).
__global__ __launch_bounds__(256)
void prep_A(const float* __restrict__ A, u16* __restrict__ Af_hi, u16* __restrict__ Af_lo){
    size_t i = (size_t)blockIdx.x*256 + threadIdx.x;   // 2,097,152 total
    int lane = (int)(i & 63);
    int kt   = (int)((i>>6) & 127);
    int rb   = (int)(i>>13);
    int m  = rb*16 + (lane&15);
    int k0 = kt*32 + ((lane>>4)<<3);
    const float* src = A + (size_t)m*NN + k0;
    float4 a = *(const float4*)src;
    float4 b = *(const float4*)(src+4);
    float v[8] = {a.x,a.y,a.z,a.w,b.x,b.y,b.z,b.w};
    bf16x8 vh, vl;
    #pragma unroll
    for (int j=0;j<8;++j){
        u16 h = f2bf(v[j]);
        vh[j] = (short)h;
        vl[j] = (short)f2bf(v[j]-bf2f(h));
    }
    ((bf16x8*)Af_hi)[i] = vh;
    ((bf16x8*)Af_lo)[i] = vl;
}

// Initial G (h=c=0 -> G cols = biases), fragment-ordered bf16 hi/lo; zero h/c state.
// B-fragment addr (u16 units): ((kt*4 + ct)*64 + (n&15) + ((kr>>3)<<4))*8 + (kr&7)
__global__ __launch_bounds__(256)
void init_G(u16* __restrict__ Gh, u16* __restrict__ Gl,
            float* __restrict__ hs, float* __restrict__ cs,
            const float* __restrict__ bgh, const float* __restrict__ bgc){
    int i = blockIdx.x*256 + threadIdx.x;   // k*64+n, 262144 total
    int k = i>>6, n = i&63;
    float v = (n<HH) ? bgh[n] : bgc[n-HH];
    u16 h = f2bf(v);
    u16 l = f2bf(v - bf2f(h));
    int kt = k>>5, kr = k&31;
    size_t idx = (((size_t)kt*4 + (n>>4))*64 + ((n&15) + ((kr>>3)<<4)))*8 + (kr&7);
    Gh[idx] = h; Gl[idx] = l;
    if (i < NN*HH){ hs[i]=0.f; cs[i]=0.f; }
}

// One time step. 512 threads = 8 waves. Block owns 16 node-rows.
// Phase 1: wave w accumulates k-range [w*512, w*512+512) via split-bf16 MFMA
//          (3 passes: hi*hi + lo*hi + hi*lo), LDS reduce over 8 waves, tanh.
// Phase 2 (tid<256): LSTM cell + fusion + next-step G (fragment order) + head.
__global__ __launch_bounds__(512)
void step_kernel(const u16* __restrict__ Af_hi, const u16* __restrict__ Af_lo,
                 const u16* __restrict__ Gin_hi, const u16* __restrict__ Gin_lo,
                 u16* __restrict__ Gout_hi, u16* __restrict__ Gout_lo,
                 const float* __restrict__ x, const float* __restrict__ W_out,
                 const float* __restrict__ b_out,
                 const float* __restrict__ Wgh, const float* __restrict__ bgh,
                 const float* __restrict__ Wgc, const float* __restrict__ bgc,
                 const float* __restrict__ Whc, const float* __restrict__ Whp,
                 const float* __restrict__ bh,
                 const float* __restrict__ Wcc, const float* __restrict__ Wcp,
                 const float* __restrict__ bc,
                 const float* __restrict__ K, const float* __restrict__ R,
                 const float* __restrict__ bias,
                 float* __restrict__ h_state, float* __restrict__ c_state,
                 float* __restrict__ out, int t)
{
    __shared__ float smem[8192 + 1040 + 3424];   // 50.6 KB
    float* ldsRed = smem;            // [8][16][64] phase-1 partials
    float* gts    = smem;            // alias: [16][129] gates (phase 2)
    float* hgcg   = smem + 8192;     // [16][65] tanh(A@G) result
    float* sarr   = smem + 8192 + 1040;
    float* hprev = sarr;             // [16][33]
    float* cprev = sarr + 528;
    float* hcur  = sarr + 1056;
    float* ccur  = sarr + 1584;
    float* hupd  = sarr + 2112;
    float* cupd  = sarr + 2640;
    float* xs    = sarr + 3168;      // [16][16]

    const int tid  = threadIdx.x;
    const int w    = tid >> 6;       // wave 0..7 = k-eighth
    const int lane = tid & 63;
    const int rb   = blockIdx.x;     // row-band (16 rows)

    // ---------------- phase 1: split-bf16 MFMA matmul ----------------
    f32x4 acc[4] = {};
    const bf16x8* Ah = (const bf16x8*)Af_hi;
    const bf16x8* Al = (const bf16x8*)Af_lo;
    const bf16x8* Gh = (const bf16x8*)Gin_hi;
    const bf16x8* Gl = (const bf16x8*)Gin_lo;
    const int ktBeg = w*16, ktEnd = ktBeg + 16;
    size_t aIdx = ((size_t)rb*128 + ktBeg)*64 + lane;
    size_t gIdx = ((size_t)ktBeg*4)*64 + lane;
    #pragma unroll 2
    for (int kt = ktBeg; kt < ktEnd; ++kt, aIdx += 64, gIdx += 256){
        bf16x8 ah = Ah[aIdx], al = Al[aIdx];
        bf16x8 g0 = Gh[gIdx], g1 = Gh[gIdx+64], g2 = Gh[gIdx+128], g3 = Gh[gIdx+192];
        bf16x8 l0 = Gl[gIdx], l1 = Gl[gIdx+64], l2 = Gl[gIdx+128], l3 = Gl[gIdx+192];
        acc[0] = __builtin_amdgcn_mfma_f32_16x16x32_bf16(ah,g0,acc[0],0,0,0);
        acc[1] = __builtin_amdgcn_mfma_f32_16x16x32_bf16(ah,g1,acc[1],0,0,0);
        acc[2] = __builtin_amdgcn_mfma_f32_16x16x32_bf16(ah,g2,acc[2],0,0,0);
        acc[3] = __builtin_amdgcn_mfma_f32_16x16x32_bf16(ah,g3,acc[3],0,0,0);
        acc[0] = __builtin_amdgcn_mfma_f32_16x16x32_bf16(al,g0,acc[0],0,0,0);
        acc[1] = __builtin_amdgcn_mfma_f32_16x16x32_bf16(al,g1,acc[1],0,0,0);
        acc[2] = __builtin_amdgcn_mfma_f32_16x16x32_bf16(al,g2,acc[2],0,0,0);
        acc[3] = __builtin_amdgcn_mfma_f32_16x16x32_bf16(al,g3,acc[3],0,0,0);
        acc[0] = __builtin_amdgcn_mfma_f32_16x16x32_bf16(ah,l0,acc[0],0,0,0);
        acc[1] = __builtin_amdgcn_mfma_f32_16x16x32_bf16(ah,l1,acc[1],0,0,0);
        acc[2] = __builtin_amdgcn_mfma_f32_16x16x32_bf16(ah,l2,acc[2],0,0,0);
        acc[3] = __builtin_amdgcn_mfma_f32_16x16x32_bf16(ah,l3,acc[3],0,0,0);
    }
    // C/D layout (m89): col = lane&15, row = (lane>>4)*4 + reg
    #pragma unroll
    for (int ct = 0; ct < 4; ++ct)
        #pragma unroll
        for (int r = 0; r < 4; ++r){
            int row = ((lane>>4)<<2) + r;
            int col = ct*16 + (lane&15);
            ldsRed[(w<<10) + row*64 + col] = acc[ct][r];
        }
    __syncthreads();
    {   // reduce 8 partials + tanh -> hgcg
        int o = tid*2;
        #pragma unroll
        for (int q = 0; q < 2; ++q){
            int oo = o + q;
            float s = 0.f;
            #pragma unroll
            for (int ww = 0; ww < 8; ++ww) s += ldsRed[(ww<<10) + oo];
            hgcg[(oo>>6)*65 + (oo&63)] = thf(s);
        }
    }
    __syncthreads();

    // ---------------- phase 2: row-local (first 256 threads) ----------------
    const int r2 = tid >> 4;
    const int j  = tid & 15;
    const int d0 = 2*j, d1 = 2*j + 1;
    const int row = rb*16 + (r2 & 15);

    if (tid < 256){
        float2 hp = *(const float2*)(h_state + (size_t)row*HH + d0);
        float2 cp = *(const float2*)(c_state + (size_t)row*HH + d0);
        hprev[r2*33 + d0] = hp.x; hprev[r2*33 + d1] = hp.y;
        cprev[r2*33 + d0] = cp.x; cprev[r2*33 + d1] = cp.y;
        xs[r2*16 + j] = x[((size_t)row*TT + t)*FF + j];
    }
    __syncthreads();

    if (tid < 256){
        float g8[8];
        #pragma unroll
        for (int q = 0; q < 8; ++q) g8[q] = bias[j*8 + q];
        #pragma unroll
        for (int f = 0; f < FF; ++f){
            float xv = xs[r2*16 + f];
            const float4* k4 = (const float4*)(K + f*128 + j*8);
            float4 ka = k4[0], kb = k4[1];
            g8[0] += xv*ka.x; g8[1] += xv*ka.y; g8[2] += xv*ka.z; g8[3] += xv*ka.w;
            g8[4] += xv*kb.x; g8[5] += xv*kb.y; g8[6] += xv*kb.z; g8[7] += xv*kb.w;
        }
        #pragma unroll
        for (int i = 0; i < HH; ++i){
            float hv = hprev[r2*33 + i];
            const float4* r4 = (const float4*)(R + i*128 + j*8);
            float4 ra = r4[0], rb4 = r4[1];
            g8[0] += hv*ra.x; g8[1] += hv*ra.y; g8[2] += hv*ra.z; g8[3] += hv*ra.w;
            g8[4] += hv*rb4.x; g8[5] += hv*rb4.y; g8[6] += hv*rb4.z; g8[7] += hv*rb4.w;
        }
        #pragma unroll
        for (int q = 0; q < 8; ++q) gts[r2*129 + j*8 + q] = g8[q];
    }
    __syncthreads();

    if (tid < 256){
        float gi0 = gts[r2*129 + d0],      gi1 = gts[r2*129 + d1];
        float gf0 = gts[r2*129 + 32 + d0], gf1 = gts[r2*129 + 32 + d1];
        float gg0 = gts[r2*129 + 64 + d0], gg1 = gts[r2*129 + 64 + d1];
        float go0 = gts[r2*129 + 96 + d0], go1 = gts[r2*129 + 96 + d1];
        float cc0 = sigf(gf0)*cprev[r2*33 + d0] + sigf(gi0)*thf(gg0);
        float cc1 = sigf(gf1)*cprev[r2*33 + d1] + sigf(gi1)*thf(gg1);
        float hc0 = sigf(go0)*thf(cc0);
        float hc1 = sigf(go1)*thf(cc1);
        hcur[r2*33 + d0] = hc0; hcur[r2*33 + d1] = hc1;
        ccur[r2*33 + d0] = cc0; ccur[r2*33 + d1] = cc1;
    }
    __syncthreads();

    float hu0, hu1, cu0, cu1;
    if (tid < 256){
        float s0 = bh[d0], s1 = bh[d1], u0 = bc[d0], u1 = bc[d1];
        #pragma unroll
        for (int i = 0; i < HH; ++i){
            float hcv = hcur[r2*33 + i], hgv = hgcg[r2*65 + i];
            float ccv = ccur[r2*33 + i], cgv = hgcg[r2*65 + 32 + i];
            float2 whc = *(const float2*)(Whc + i*32 + d0);
            float2 whp = *(const float2*)(Whp + i*32 + d0);
            float2 wcc = *(const float2*)(Wcc + i*32 + d0);
            float2 wcp = *(const float2*)(Wcp + i*32 + d0);
            s0 += hcv*whc.x + hgv*whp.x;  s1 += hcv*whc.y + hgv*whp.y;
            u0 += ccv*wcc.x + cgv*wcp.x;  u1 += ccv*wcc.y + cgv*wcp.y;
        }
        hu0 = sigf(s0); hu1 = sigf(s1); cu0 = sigf(u0); cu1 = sigf(u1);
        hupd[r2*33 + d0] = hu0; hupd[r2*33 + d1] = hu1;
        cupd[r2*33 + d0] = cu0; cupd[r2*33 + d1] = cu1;
        *(float2*)(h_state + (size_t)row*HH + d0) = make_float2(hu0, hu1);
        *(float2*)(c_state + (size_t)row*HH + d0) = make_float2(cu0, cu1);
    }
    __syncthreads();

    if (tid < 256){
        // G(t+1) for this row, written straight into B-fragment order
        float gh0 = bgh[d0], gh1 = bgh[d1], gc0 = bgc[d0], gc1 = bgc[d1];
        #pragma unroll
        for (int i = 0; i < HH; ++i){
            float hv = hupd[r2*33 + i], cv = cupd[r2*33 + i];
            float2 wgh = *(const float2*)(Wgh + i*32 + d0);
            float2 wgc = *(const float2*)(Wgc + i*32 + d0);
            gh0 += hv*wgh.x; gh1 += hv*wgh.y;
            gc0 += cv*wgc.x; gc1 += cv*wgc.y;
        }
        const int kt = row>>5, kr = row&31;
        const size_t tb = ((size_t)kt*4)*64;
        auto wfrag = [&](int n, float v){
            u16 h = f2bf(v);
            u16 l = f2bf(v - bf2f(h));
            size_t idx = (tb + (size_t)(n>>4)*64 + ((n&15) + ((kr>>3)<<4)))*8 + (kr&7);
            Gout_hi[idx] = h; Gout_lo[idx] = l;
        };
        wfrag(d0, gh0); wfrag(d1, gh1); wfrag(HH + d0, gc0); wfrag(HH + d1, gc1);

        // fused output head
        float p = hu0*W_out[d0] + hu1*W_out[d1];
        #pragma unroll
        for (int off = 8; off; off >>= 1) p += __shfl_down(p, off, 16);
        if (j == 0) out[(size_t)t*NN + row] = p + b_out[0];
    }
}

extern "C" void kernel_launch(void* const* d_in, const int* in_sizes, int n_in,
                              void* d_out, int out_size, void* d_ws, size_t ws_size,
                              hipStream_t stream)
{
    const float* x     = (const float*)d_in[0];
    const float* A     = (const float*)d_in[1];
    const float* W_out = (const float*)d_in[2];
    const float* b_out = (const float*)d_in[3];
    const float* Wgh   = (const float*)d_in[4];
    const float* bgh   = (const float*)d_in[5];
    const float* Wgc   = (const float*)d_in[6];
    const float* bgc   = (const float*)d_in[7];
    const float* Whc   = (const float*)d_in[8];
    const float* Whp   = (const float*)d_in[9];
    const float* bh    = (const float*)d_in[10];
    const float* Wcc   = (const float*)d_in[11];
    const float* Wcp   = (const float*)d_in[12];
    const float* bc    = (const float*)d_in[13];
    const float* K     = (const float*)d_in[14];
    const float* R     = (const float*)d_in[15];
    const float* bias  = (const float*)d_in[16];
    float* out = (float*)d_out;

    // ws layout: Af_hi 32MB | Af_lo 32MB | G frag double-buffer 4x512KB | h/c state 1MB
    u16* Af_hi = (u16*)d_ws;
    u16* Af_lo = Af_hi + (size_t)NN*NN;
    u16* G0h = Af_lo + (size_t)NN*NN;
    u16* G0l = G0h + (size_t)NN*64;
    u16* G1h = G0l + (size_t)NN*64;
    u16* G1l = G1h + (size_t)NN*64;
    float* hs = (float*)(G1l + (size_t)NN*64);
    float* cs = hs + (size_t)NN*HH;

    prep_A<<<dim3(8192), dim3(256), 0, stream>>>(A, Af_hi, Af_lo);
    init_G<<<dim3(1024), dim3(256), 0, stream>>>(G0h, G0l, hs, cs, bgh, bgc);

    for (int t = 0; t < TT; ++t){
        const u16* Gih = (t & 1) ? G1h : G0h;
        const u16* Gil = (t & 1) ? G1l : G0l;
        u16* Goh = (t & 1) ? G0h : G1h;
        u16* Gol = (t & 1) ? G0l : G1l;
        step_kernel<<<dim3(NN/16), dim3(512), 0, stream>>>(
            Af_hi, Af_lo, Gih, Gil, Goh, Gol,
            x, W_out, b_out, Wgh, bgh, Wgc, bgc, Whc, Whp, bh,
            Wcc, Wcp, bc, K, R, bias, hs, cs, out, t);
    }
}

// Round 3
// 9165.850 us; speedup vs baseline: 4.5894x; 1.2399x over previous
//
#include <hip/hip_runtime.h>
#include <math.h>

#define NN 4096
#define TT 365
#define FF 16
#define HH 32

typedef unsigned short u16;
typedef _Float16 f16;
typedef __attribute__((ext_vector_type(8))) _Float16 f16x8;
typedef __attribute__((ext_vector_type(4))) float f32x4;

__device__ __forceinline__ float sigf(float x){ return 1.0f/(1.0f+__expf(-x)); }
__device__ __forceinline__ float thf(float x){
    x = fminf(fmaxf(x,-15.0f),15.0f);
    float e = __expf(2.0f*x);
    return (e-1.0f)/(e+1.0f);
}

// Pre-pack A (fp32 [4096][4096]) into MFMA A-fragment order, split fp16 hi/lo.
// Fragment addr (f16x8 units): (rb*128 + kt)*64 + lane
//   lane&15 = local row m, lane>>4 = k-subgroup (8 consecutive k each).
__global__ __launch_bounds__(256)
void prep_A(const float* __restrict__ A, f16* __restrict__ Af_hi, f16* __restrict__ Af_lo){
    size_t i = (size_t)blockIdx.x*256 + threadIdx.x;   // 2,097,152 total
    int lane = (int)(i & 63);
    int kt   = (int)((i>>6) & 127);
    int rb   = (int)(i>>13);
    int m  = rb*16 + (lane&15);
    int k0 = kt*32 + ((lane>>4)<<3);
    const float* src = A + (size_t)m*NN + k0;
    float4 a = *(const float4*)src;
    float4 b = *(const float4*)(src+4);
    float v[8] = {a.x,a.y,a.z,a.w,b.x,b.y,b.z,b.w};
    f16x8 vh, vl;
    #pragma unroll
    for (int j=0;j<8;++j){
        f16 h = (f16)v[j];
        vh[j] = h;
        vl[j] = (f16)(v[j] - (float)h);
    }
    ((f16x8*)Af_hi)[i] = vh;
    ((f16x8*)Af_lo)[i] = vl;
}

// Initial G (h=c=0 -> G cols = biases), fragment-ordered fp16; zero h/c state.
// B-fragment addr (f16 units): ((kt*4 + ct)*64 + (n&15) + ((kr>>3)<<4))*8 + (kr&7)
__global__ __launch_bounds__(256)
void init_G(f16* __restrict__ G,
            float* __restrict__ hs, float* __restrict__ cs,
            const float* __restrict__ bgh, const float* __restrict__ bgc){
    int i = blockIdx.x*256 + threadIdx.x;   // k*64+n, 262144 total
    int k = i>>6, n = i&63;
    float v = (n<HH) ? bgh[n] : bgc[n-HH];
    int kt = k>>5, kr = k&31;
    size_t idx = (((size_t)kt*4 + (n>>4))*64 + ((n&15) + ((kr>>3)<<4)))*8 + (kr&7);
    G[idx] = (f16)v;
    if (i < NN*HH){ hs[i]=0.f; cs[i]=0.f; }
}

// One time step. 512 threads = 8 waves. Block owns 16 node-rows.
// Phase 1: wave w accumulates k-range [w*512, w*512+512) via fp16 MFMA
//          2-pass (A_hi*G + A_lo*G; A split makes A effectively exact,
//          G single fp16 rel err 2^-12 -> pre-tanh err ~2e-4, loop gain <<1).
// Phase 2 (tid<256): LSTM cell + fusion + next-step G (fragment order) + head.
__global__ __launch_bounds__(512)
void step_kernel(const f16* __restrict__ Af_hi, const f16* __restrict__ Af_lo,
                 const f16* __restrict__ Gin, f16* __restrict__ Gout,
                 const float* __restrict__ x, const float* __restrict__ W_out,
                 const float* __restrict__ b_out,
                 const float* __restrict__ Wgh, const float* __restrict__ bgh,
                 const float* __restrict__ Wgc, const float* __restrict__ bgc,
                 const float* __restrict__ Whc, const float* __restrict__ Whp,
                 const float* __restrict__ bh,
                 const float* __restrict__ Wcc, const float* __restrict__ Wcp,
                 const float* __restrict__ bc,
                 const float* __restrict__ K, const float* __restrict__ R,
                 const float* __restrict__ bias,
                 float* __restrict__ h_state, float* __restrict__ c_state,
                 float* __restrict__ out, int t)
{
    __shared__ float smem[8192 + 1040 + 3424];   // 50.6 KB
    float* ldsRed = smem;            // [8][16][64] phase-1 partials
    float* gts    = smem;            // alias: [16][129] gates (phase 2)
    float* hgcg   = smem + 8192;     // [16][65] tanh(A@G) result
    float* sarr   = smem + 8192 + 1040;
    float* hprev = sarr;             // [16][33]
    float* cprev = sarr + 528;
    float* hcur  = sarr + 1056;
    float* ccur  = sarr + 1584;
    float* hupd  = sarr + 2112;
    float* cupd  = sarr + 2640;
    float* xs    = sarr + 3168;      // [16][16]

    const int tid  = threadIdx.x;
    const int w    = tid >> 6;       // wave 0..7 = k-eighth
    const int lane = tid & 63;
    const int rb   = blockIdx.x;     // row-band (16 rows)

    // ---------------- phase 1: split-fp16 MFMA matmul ----------------
    f32x4 acc[4] = {};
    const f16x8* Ah = (const f16x8*)Af_hi;
    const f16x8* Al = (const f16x8*)Af_lo;
    const f16x8* Gf = (const f16x8*)Gin;
    const int ktBeg = w*16, ktEnd = ktBeg + 16;
    size_t aIdx = ((size_t)rb*128 + ktBeg)*64 + lane;
    size_t gIdx = ((size_t)ktBeg*4)*64 + lane;
    #pragma unroll 4
    for (int kt = ktBeg; kt < ktEnd; ++kt, aIdx += 64, gIdx += 256){
        f16x8 ah = Ah[aIdx], al = Al[aIdx];
        f16x8 g0 = Gf[gIdx], g1 = Gf[gIdx+64], g2 = Gf[gIdx+128], g3 = Gf[gIdx+192];
        acc[0] = __builtin_amdgcn_mfma_f32_16x16x32_f16(ah,g0,acc[0],0,0,0);
        acc[1] = __builtin_amdgcn_mfma_f32_16x16x32_f16(ah,g1,acc[1],0,0,0);
        acc[2] = __builtin_amdgcn_mfma_f32_16x16x32_f16(ah,g2,acc[2],0,0,0);
        acc[3] = __builtin_amdgcn_mfma_f32_16x16x32_f16(ah,g3,acc[3],0,0,0);
        acc[0] = __builtin_amdgcn_mfma_f32_16x16x32_f16(al,g0,acc[0],0,0,0);
        acc[1] = __builtin_amdgcn_mfma_f32_16x16x32_f16(al,g1,acc[1],0,0,0);
        acc[2] = __builtin_amdgcn_mfma_f32_16x16x32_f16(al,g2,acc[2],0,0,0);
        acc[3] = __builtin_amdgcn_mfma_f32_16x16x32_f16(al,g3,acc[3],0,0,0);
    }
    // C/D layout (m89): col = lane&15, row = (lane>>4)*4 + reg
    #pragma unroll
    for (int ct = 0; ct < 4; ++ct)
        #pragma unroll
        for (int r = 0; r < 4; ++r){
            int row = ((lane>>4)<<2) + r;
            int col = ct*16 + (lane&15);
            ldsRed[(w<<10) + row*64 + col] = acc[ct][r];
        }
    __syncthreads();
    {   // reduce 8 partials + tanh -> hgcg
        int o = tid*2;
        #pragma unroll
        for (int q = 0; q < 2; ++q){
            int oo = o + q;
            float s = 0.f;
            #pragma unroll
            for (int ww = 0; ww < 8; ++ww) s += ldsRed[(ww<<10) + oo];
            hgcg[(oo>>6)*65 + (oo&63)] = thf(s);
        }
    }
    __syncthreads();

    // ---------------- phase 2: row-local (first 256 threads) ----------------
    const int r2 = tid >> 4;
    const int j  = tid & 15;
    const int d0 = 2*j, d1 = 2*j + 1;
    const int row = rb*16 + (r2 & 15);

    if (tid < 256){
        float2 hp = *(const float2*)(h_state + (size_t)row*HH + d0);
        float2 cp = *(const float2*)(c_state + (size_t)row*HH + d0);
        hprev[r2*33 + d0] = hp.x; hprev[r2*33 + d1] = hp.y;
        cprev[r2*33 + d0] = cp.x; cprev[r2*33 + d1] = cp.y;
        xs[r2*16 + j] = x[((size_t)row*TT + t)*FF + j];
    }
    __syncthreads();

    if (tid < 256){
        float g8[8];
        #pragma unroll
        for (int q = 0; q < 8; ++q) g8[q] = bias[j*8 + q];
        #pragma unroll
        for (int f = 0; f < FF; ++f){
            float xv = xs[r2*16 + f];
            const float4* k4 = (const float4*)(K + f*128 + j*8);
            float4 ka = k4[0], kb = k4[1];
            g8[0] += xv*ka.x; g8[1] += xv*ka.y; g8[2] += xv*ka.z; g8[3] += xv*ka.w;
            g8[4] += xv*kb.x; g8[5] += xv*kb.y; g8[6] += xv*kb.z; g8[7] += xv*kb.w;
        }
        #pragma unroll
        for (int i = 0; i < HH; ++i){
            float hv = hprev[r2*33 + i];
            const float4* r4 = (const float4*)(R + i*128 + j*8);
            float4 ra = r4[0], rb4 = r4[1];
            g8[0] += hv*ra.x; g8[1] += hv*ra.y; g8[2] += hv*ra.z; g8[3] += hv*ra.w;
            g8[4] += hv*rb4.x; g8[5] += hv*rb4.y; g8[6] += hv*rb4.z; g8[7] += hv*rb4.w;
        }
        #pragma unroll
        for (int q = 0; q < 8; ++q) gts[r2*129 + j*8 + q] = g8[q];
    }
    __syncthreads();

    if (tid < 256){
        float gi0 = gts[r2*129 + d0],      gi1 = gts[r2*129 + d1];
        float gf0 = gts[r2*129 + 32 + d0], gf1 = gts[r2*129 + 32 + d1];
        float gg0 = gts[r2*129 + 64 + d0], gg1 = gts[r2*129 + 64 + d1];
        float go0 = gts[r2*129 + 96 + d0], go1 = gts[r2*129 + 96 + d1];
        float cc0 = sigf(gf0)*cprev[r2*33 + d0] + sigf(gi0)*thf(gg0);
        float cc1 = sigf(gf1)*cprev[r2*33 + d1] + sigf(gi1)*thf(gg1);
        float hc0 = sigf(go0)*thf(cc0);
        float hc1 = sigf(go1)*thf(cc1);
        hcur[r2*33 + d0] = hc0; hcur[r2*33 + d1] = hc1;
        ccur[r2*33 + d0] = cc0; ccur[r2*33 + d1] = cc1;
    }
    __syncthreads();

    float hu0, hu1, cu0, cu1;
    if (tid < 256){
        float s0 = bh[d0], s1 = bh[d1], u0 = bc[d0], u1 = bc[d1];
        #pragma unroll
        for (int i = 0; i < HH; ++i){
            float hcv = hcur[r2*33 + i], hgv = hgcg[r2*65 + i];
            float ccv = ccur[r2*33 + i], cgv = hgcg[r2*65 + 32 + i];
            float2 whc = *(const float2*)(Whc + i*32 + d0);
            float2 whp = *(const float2*)(Whp + i*32 + d0);
            float2 wcc = *(const float2*)(Wcc + i*32 + d0);
            float2 wcp = *(const float2*)(Wcp + i*32 + d0);
            s0 += hcv*whc.x + hgv*whp.x;  s1 += hcv*whc.y + hgv*whp.y;
            u0 += ccv*wcc.x + cgv*wcp.x;  u1 += ccv*wcc.y + cgv*wcp.y;
        }
        hu0 = sigf(s0); hu1 = sigf(s1); cu0 = sigf(u0); cu1 = sigf(u1);
        hupd[r2*33 + d0] = hu0; hupd[r2*33 + d1] = hu1;
        cupd[r2*33 + d0] = cu0; cupd[r2*33 + d1] = cu1;
        *(float2*)(h_state + (size_t)row*HH + d0) = make_float2(hu0, hu1);
        *(float2*)(c_state + (size_t)row*HH + d0) = make_float2(cu0, cu1);
    }
    __syncthreads();

    if (tid < 256){
        // G(t+1) for this row, written straight into B-fragment order
        float gh0 = bgh[d0], gh1 = bgh[d1], gc0 = bgc[d0], gc1 = bgc[d1];
        #pragma unroll
        for (int i = 0; i < HH; ++i){
            float hv = hupd[r2*33 + i], cv = cupd[r2*33 + i];
            float2 wgh = *(const float2*)(Wgh + i*32 + d0);
            float2 wgc = *(const float2*)(Wgc + i*32 + d0);
            gh0 += hv*wgh.x; gh1 += hv*wgh.y;
            gc0 += cv*wgc.x; gc1 += cv*wgc.y;
        }
        const int kt = row>>5, kr = row&31;
        const size_t tb = ((size_t)kt*4)*64;
        auto wfrag = [&](int n, float v){
            size_t idx = (tb + (size_t)(n>>4)*64 + ((n&15) + ((kr>>3)<<4)))*8 + (kr&7);
            Gout[idx] = (f16)v;
        };
        wfrag(d0, gh0); wfrag(d1, gh1); wfrag(HH + d0, gc0); wfrag(HH + d1, gc1);

        // fused output head
        float p = hu0*W_out[d0] + hu1*W_out[d1];
        #pragma unroll
        for (int off = 8; off; off >>= 1) p += __shfl_down(p, off, 16);
        if (j == 0) out[(size_t)t*NN + row] = p + b_out[0];
    }
}

extern "C" void kernel_launch(void* const* d_in, const int* in_sizes, int n_in,
                              void* d_out, int out_size, void* d_ws, size_t ws_size,
                              hipStream_t stream)
{
    const float* x     = (const float*)d_in[0];
    const float* A     = (const float*)d_in[1];
    const float* W_out = (const float*)d_in[2];
    const float* b_out = (const float*)d_in[3];
    const float* Wgh   = (const float*)d_in[4];
    const float* bgh   = (const float*)d_in[5];
    const float* Wgc   = (const float*)d_in[6];
    const float* bgc   = (const float*)d_in[7];
    const float* Whc   = (const float*)d_in[8];
    const float* Whp   = (const float*)d_in[9];
    const float* bh    = (const float*)d_in[10];
    const float* Wcc   = (const float*)d_in[11];
    const float* Wcp   = (const float*)d_in[12];
    const float* bc    = (const float*)d_in[13];
    const float* K     = (const float*)d_in[14];
    const float* R     = (const float*)d_in[15];
    const float* bias  = (const float*)d_in[16];
    float* out = (float*)d_out;

    // ws layout: Af_hi 32MB | Af_lo 32MB | G double-buffer 2x512KB | h/c state 1MB
    f16* Af_hi = (f16*)d_ws;
    f16* Af_lo = Af_hi + (size_t)NN*NN;
    f16* G0 = Af_lo + (size_t)NN*NN;
    f16* G1 = G0 + (size_t)NN*64;
    float* hs = (float*)(G1 + (size_t)NN*64);
    float* cs = hs + (size_t)NN*HH;

    prep_A<<<dim3(8192), dim3(256), 0, stream>>>(A, Af_hi, Af_lo);
    init_G<<<dim3(1024), dim3(256), 0, stream>>>(G0, hs, cs, bgh, bgc);

    for (int t = 0; t < TT; ++t){
        const f16* Gin = (t & 1) ? G1 : G0;
        f16*       Gout = (t & 1) ? G0 : G1;
        step_kernel<<<dim3(NN/16), dim3(512), 0, stream>>>(
            Af_hi, Af_lo, Gin, Gout,
            x, W_out, b_out, Wgh, bgh, Wgc, bgc, Whc, Whp, bh,
            Wcc, Wcp, bc, K, R, bias, hs, cs, out, t);
    }
}